// Round 1
// baseline (492.717 us; speedup 1.0000x reference)
//
#include <hip/hip_runtime.h>
#include <hip/hip_bf16.h>
#include <math.h>

#define T_TOK 1024
#define H_DIM 1024
#define NEXP 16
#define TOPK 2
#define I_DIM 512
#define ISH 1024            // I*NS for shared expert
#define NPAIR (T_TOK*TOPK)

// ---------------- router: one wave per token ----------------
__global__ __launch_bounds__(64) void k_router(const float* __restrict__ x,
        const float* __restrict__ gw, const float* __restrict__ bias,
        int* __restrict__ tok_e, float* __restrict__ tok_w, int* __restrict__ counts)
{
    int t = blockIdx.x;
    int lane = threadIdx.x;
    float acc[NEXP];
    #pragma unroll
    for (int e = 0; e < NEXP; ++e) acc[e] = 0.f;
    const float* xrow = x + (size_t)t * H_DIM;
    for (int c = lane; c < H_DIM; c += 64) {
        float xv = xrow[c];
        #pragma unroll
        for (int e = 0; e < NEXP; ++e) acc[e] += xv * gw[e * H_DIM + c];
    }
    #pragma unroll
    for (int e = 0; e < NEXP; ++e) {
        float v = acc[e];
        #pragma unroll
        for (int off = 1; off < 64; off <<= 1) v += __shfl_xor(v, off);
        acc[e] = v;
    }
    if (lane == 0) {
        float sc[NEXP], bi[NEXP];
        #pragma unroll
        for (int e = 0; e < NEXP; ++e) {
            sc[e] = 1.f / (1.f + expf(-acc[e]));
            bi[e] = sc[e] + bias[e];
        }
        int i1 = 0; float b1 = bi[0];
        for (int e = 1; e < NEXP; ++e) if (bi[e] > b1) { b1 = bi[e]; i1 = e; }
        int i2 = -1; float b2 = -1e30f;
        for (int e = 0; e < NEXP; ++e) { if (e == i1) continue; if (bi[e] > b2) { b2 = bi[e]; i2 = e; } }
        float w1 = sc[i1], w2 = sc[i2];
        float s = w1 + w2;
        w1 /= s; w2 /= s;
        tok_e[t * 2]     = i1;  tok_e[t * 2 + 1] = i2;
        tok_w[t * 2]     = w1;  tok_w[t * 2 + 1] = w2;
        atomicAdd(&counts[i1], 1);
        atomicAdd(&counts[i2], 1);
    }
}

__global__ void k_zero(int* p) { if (threadIdx.x < 16) p[threadIdx.x] = 0; }

__global__ void k_scan(const int* __restrict__ counts, int* __restrict__ offs, int* __restrict__ cursor)
{
    if (threadIdx.x == 0) {
        int s = 0;
        for (int e = 0; e < NEXP; ++e) { offs[e] = s; cursor[e] = s; s += counts[e]; }
        offs[NEXP] = s;
    }
}

__global__ void k_scatter(const int* __restrict__ tok_e, const float* __restrict__ tok_w,
                          int* __restrict__ cursor, int* __restrict__ row_token, float* __restrict__ row_w)
{
    int p = blockIdx.x * blockDim.x + threadIdx.x;
    if (p >= NPAIR) return;
    int e = tok_e[p];
    int pos = atomicAdd(&cursor[e], 1);
    row_token[pos] = p >> 1;
    row_w[pos] = tok_w[p];
}

// ---------------- routed gate_up + SwiGLU: grouped GEMM ----------------
// grid: x = I/32 n-tiles, y = e*32 + mtile
__global__ __launch_bounds__(256) void k_moe_gu(const float* __restrict__ x,
        const float* __restrict__ wgu, const int* __restrict__ offs,
        const int* __restrict__ row_token, float* __restrict__ act)
{
    int e  = blockIdx.y >> 5;
    int mt = blockIdx.y & 31;
    int rbeg = offs[e], rend = offs[e + 1];
    int m0 = rbeg + mt * 32;
    if (m0 >= rend) return;
    int mcnt = min(32, rend - m0);
    int n0 = blockIdx.x * 32;

    __shared__ float As[32][33];
    __shared__ float Bg[32][33];
    __shared__ float Bu[32][33];
    __shared__ int   toks[32];

    int tid = threadIdx.x;
    if (tid < 32) toks[tid] = row_token[m0 + min(tid, mcnt - 1)];
    __syncthreads();

    int col = tid & 31;
    int rg  = (tid >> 5) << 2;
    float ag[4] = {0,0,0,0}, au[4] = {0,0,0,0};

    const float* B = wgu + (size_t)e * (2 * I_DIM) * H_DIM;
    int lr = tid >> 3;            // 0..31
    int lk = (tid & 7) << 2;      // 0,4,..,28
    const float* asrc  = x + (size_t)toks[lr] * H_DIM + lk;
    const float* bgsrc = B + (size_t)(n0 + lr) * H_DIM + lk;
    const float* busrc = B + (size_t)(I_DIM + n0 + lr) * H_DIM + lk;

    for (int k0 = 0; k0 < H_DIM; k0 += 32) {
        float4 va = *(const float4*)(asrc + k0);
        float4 vg = *(const float4*)(bgsrc + k0);
        float4 vu = *(const float4*)(busrc + k0);
        As[lr][lk] = va.x; As[lr][lk+1] = va.y; As[lr][lk+2] = va.z; As[lr][lk+3] = va.w;
        Bg[lr][lk] = vg.x; Bg[lr][lk+1] = vg.y; Bg[lr][lk+2] = vg.z; Bg[lr][lk+3] = vg.w;
        Bu[lr][lk] = vu.x; Bu[lr][lk+1] = vu.y; Bu[lr][lk+2] = vu.z; Bu[lr][lk+3] = vu.w;
        __syncthreads();
        #pragma unroll
        for (int kk = 0; kk < 32; ++kk) {
            float bg = Bg[col][kk], bu = Bu[col][kk];
            #pragma unroll
            for (int j = 0; j < 4; ++j) {
                float a = As[rg + j][kk];
                ag[j] = fmaf(a, bg, ag[j]);
                au[j] = fmaf(a, bu, au[j]);
            }
        }
        __syncthreads();
    }
    #pragma unroll
    for (int j = 0; j < 4; ++j) {
        int r = rg + j;
        if (r < mcnt) {
            float g = ag[j];
            float val = (g / (1.f + expf(-g))) * au[j];
            act[(size_t)(m0 + r) * I_DIM + n0 + col] = val;
        }
    }
}

// ---------------- routed down + weighted combine (atomicAdd) ----------------
// grid: x = H/32 n-tiles, y = e*32 + mtile
__global__ __launch_bounds__(256) void k_moe_down(const float* __restrict__ act,
        const float* __restrict__ wd, const int* __restrict__ offs,
        const int* __restrict__ row_token, const float* __restrict__ row_w,
        float* __restrict__ out)
{
    int e  = blockIdx.y >> 5;
    int mt = blockIdx.y & 31;
    int rbeg = offs[e], rend = offs[e + 1];
    int m0 = rbeg + mt * 32;
    if (m0 >= rend) return;
    int mcnt = min(32, rend - m0);
    int n0 = blockIdx.x * 32;

    __shared__ float As[32][33];
    __shared__ float Bs[32][33];

    int tid = threadIdx.x;
    int col = tid & 31;
    int rg  = (tid >> 5) << 2;
    float acc[4] = {0,0,0,0};

    const float* B = wd + (size_t)e * H_DIM * I_DIM;
    int lr = tid >> 3;
    int lk = (tid & 7) << 2;
    const float* asrc = act + (size_t)(m0 + lr) * I_DIM + lk;
    const float* bsrc = B + (size_t)(n0 + lr) * I_DIM + lk;

    for (int k0 = 0; k0 < I_DIM; k0 += 32) {
        float4 va = *(const float4*)(asrc + k0);
        float4 vb = *(const float4*)(bsrc + k0);
        As[lr][lk] = va.x; As[lr][lk+1] = va.y; As[lr][lk+2] = va.z; As[lr][lk+3] = va.w;
        Bs[lr][lk] = vb.x; Bs[lr][lk+1] = vb.y; Bs[lr][lk+2] = vb.z; Bs[lr][lk+3] = vb.w;
        __syncthreads();
        #pragma unroll
        for (int kk = 0; kk < 32; ++kk) {
            float b = Bs[col][kk];
            #pragma unroll
            for (int j = 0; j < 4; ++j) acc[j] = fmaf(As[rg + j][kk], b, acc[j]);
        }
        __syncthreads();
    }
    #pragma unroll
    for (int j = 0; j < 4; ++j) {
        int r = rg + j;
        if (r < mcnt) {
            int t = row_token[m0 + r];
            atomicAdd(&out[(size_t)t * H_DIM + n0 + col], row_w[m0 + r] * acc[j]);
        }
    }
}

// ---------------- shared expert gate_up + SwiGLU ----------------
// grid: x = ISH/32, y = T/32
__global__ __launch_bounds__(256) void k_sh_gu(const float* __restrict__ x,
        const float* __restrict__ sgu, float* __restrict__ act2)
{
    int m0 = blockIdx.y * 32;
    int n0 = blockIdx.x * 32;

    __shared__ float As[32][33];
    __shared__ float Bg[32][33];
    __shared__ float Bu[32][33];

    int tid = threadIdx.x;
    int col = tid & 31;
    int rg  = (tid >> 5) << 2;
    float ag[4] = {0,0,0,0}, au[4] = {0,0,0,0};

    int lr = tid >> 3;
    int lk = (tid & 7) << 2;
    const float* asrc  = x + (size_t)(m0 + lr) * H_DIM + lk;
    const float* bgsrc = sgu + (size_t)(n0 + lr) * H_DIM + lk;
    const float* busrc = sgu + (size_t)(ISH + n0 + lr) * H_DIM + lk;

    for (int k0 = 0; k0 < H_DIM; k0 += 32) {
        float4 va = *(const float4*)(asrc + k0);
        float4 vg = *(const float4*)(bgsrc + k0);
        float4 vu = *(const float4*)(busrc + k0);
        As[lr][lk] = va.x; As[lr][lk+1] = va.y; As[lr][lk+2] = va.z; As[lr][lk+3] = va.w;
        Bg[lr][lk] = vg.x; Bg[lr][lk+1] = vg.y; Bg[lr][lk+2] = vg.z; Bg[lr][lk+3] = vg.w;
        Bu[lr][lk] = vu.x; Bu[lr][lk+1] = vu.y; Bu[lr][lk+2] = vu.z; Bu[lr][lk+3] = vu.w;
        __syncthreads();
        #pragma unroll
        for (int kk = 0; kk < 32; ++kk) {
            float bg = Bg[col][kk], bu = Bu[col][kk];
            #pragma unroll
            for (int j = 0; j < 4; ++j) {
                float a = As[rg + j][kk];
                ag[j] = fmaf(a, bg, ag[j]);
                au[j] = fmaf(a, bu, au[j]);
            }
        }
        __syncthreads();
    }
    #pragma unroll
    for (int j = 0; j < 4; ++j) {
        float g = ag[j];
        float val = (g / (1.f + expf(-g))) * au[j];
        act2[(size_t)(m0 + rg + j) * ISH + n0 + col] = val;
    }
}

// ---------------- shared expert down: writes out directly ----------------
// grid: x = H/32, y = T/32
__global__ __launch_bounds__(256) void k_sh_down(const float* __restrict__ act2,
        const float* __restrict__ sd, float* __restrict__ out)
{
    int m0 = blockIdx.y * 32;
    int n0 = blockIdx.x * 32;

    __shared__ float As[32][33];
    __shared__ float Bs[32][33];

    int tid = threadIdx.x;
    int col = tid & 31;
    int rg  = (tid >> 5) << 2;
    float acc[4] = {0,0,0,0};

    int lr = tid >> 3;
    int lk = (tid & 7) << 2;
    const float* asrc = act2 + (size_t)(m0 + lr) * ISH + lk;
    const float* bsrc = sd + (size_t)(n0 + lr) * ISH + lk;

    for (int k0 = 0; k0 < ISH; k0 += 32) {
        float4 va = *(const float4*)(asrc + k0);
        float4 vb = *(const float4*)(bsrc + k0);
        As[lr][lk] = va.x; As[lr][lk+1] = va.y; As[lr][lk+2] = va.z; As[lr][lk+3] = va.w;
        Bs[lr][lk] = vb.x; Bs[lr][lk+1] = vb.y; Bs[lr][lk+2] = vb.z; Bs[lr][lk+3] = vb.w;
        __syncthreads();
        #pragma unroll
        for (int kk = 0; kk < 32; ++kk) {
            float b = Bs[col][kk];
            #pragma unroll
            for (int j = 0; j < 4; ++j) acc[j] = fmaf(As[rg + j][kk], b, acc[j]);
        }
        __syncthreads();
    }
    #pragma unroll
    for (int j = 0; j < 4; ++j)
        out[(size_t)(m0 + rg + j) * H_DIM + n0 + col] = acc[j];
}

extern "C" void kernel_launch(void* const* d_in, const int* in_sizes, int n_in,
                              void* d_out, int out_size, void* d_ws, size_t ws_size,
                              hipStream_t stream)
{
    (void)in_sizes; (void)n_in; (void)out_size; (void)ws_size;
    const float* x    = (const float*)d_in[0];
    const float* gw   = (const float*)d_in[1];
    const float* bias = (const float*)d_in[2];
    const float* wgu  = (const float*)d_in[3];
    const float* wd   = (const float*)d_in[4];
    const float* sgu  = (const float*)d_in[5];
    const float* sd   = (const float*)d_in[6];
    float* out = (float*)d_out;

    char* ws = (char*)d_ws;
    int*   counts    = (int*)(ws);
    int*   cursor    = (int*)(ws + 64);
    int*   offs      = (int*)(ws + 128);
    int*   tok_e     = (int*)(ws + 256);
    int*   row_token = (int*)(ws + 256 + 8192);
    float* tok_w     = (float*)(ws + 256 + 16384);
    float* row_w     = (float*)(ws + 256 + 24576);
    float* act       = (float*)(ws + 40960);                 // [2048, 512]
    float* act2      = (float*)(ws + 40960 + 4194304);       // [1024, 1024]

    k_zero<<<1, 64, 0, stream>>>(counts);
    k_router<<<T_TOK, 64, 0, stream>>>(x, gw, bias, tok_e, tok_w, counts);
    k_scan<<<1, 64, 0, stream>>>(counts, offs, cursor);
    k_scatter<<<NPAIR / 256, 256, 0, stream>>>(tok_e, tok_w, cursor, row_token, row_w);
    k_moe_gu<<<dim3(I_DIM / 32, NEXP * 32), 256, 0, stream>>>(x, wgu, offs, row_token, act);
    k_sh_gu<<<dim3(ISH / 32, T_TOK / 32), 256, 0, stream>>>(x, sgu, act2);
    k_sh_down<<<dim3(H_DIM / 32, T_TOK / 32), 256, 0, stream>>>(act2, sd, out);
    k_moe_down<<<dim3(H_DIM / 32, NEXP * 32), 256, 0, stream>>>(act, wd, offs, row_token, row_w, out);
}

// Round 2
// 120.973 us; speedup vs baseline: 4.0730x; 4.0730x over previous
//
#include <hip/hip_runtime.h>
#include <math.h>

#define T_TOK 1024
#define H_DIM 1024
#define NEXP  16
#define I_DIM 512
#define ISH   1024
#define NPAIR (T_TOK*2)

typedef __bf16 bf16;
typedef __bf16 bf16x4 __attribute__((ext_vector_type(4)));
typedef __bf16 bf16x8 __attribute__((ext_vector_type(8)));
typedef float  f32x4  __attribute__((ext_vector_type(4)));

#define MFMA(a,b,c) __builtin_amdgcn_mfma_f32_16x16x32_bf16(a,b,c,0,0,0)

// ---------------- router: one wave per token ----------------
__global__ __launch_bounds__(64) void k_router(const float* __restrict__ x,
        const float* __restrict__ gw, const float* __restrict__ bias,
        int* __restrict__ tok_e, float* __restrict__ tok_w, int* __restrict__ counts)
{
    int t = blockIdx.x;
    int lane = threadIdx.x;
    float acc[NEXP];
    #pragma unroll
    for (int e = 0; e < NEXP; ++e) acc[e] = 0.f;
    const float* xrow = x + (size_t)t * H_DIM;
    for (int c = lane; c < H_DIM; c += 64) {
        float xv = xrow[c];
        #pragma unroll
        for (int e = 0; e < NEXP; ++e) acc[e] += xv * gw[e * H_DIM + c];
    }
    #pragma unroll
    for (int e = 0; e < NEXP; ++e) {
        float v = acc[e];
        #pragma unroll
        for (int off = 1; off < 64; off <<= 1) v += __shfl_xor(v, off);
        acc[e] = v;
    }
    if (lane == 0) {
        float sc[NEXP], bi[NEXP];
        #pragma unroll
        for (int e = 0; e < NEXP; ++e) {
            sc[e] = 1.f / (1.f + expf(-acc[e]));
            bi[e] = sc[e] + bias[e];
        }
        int i1 = 0; float b1 = bi[0];
        for (int e = 1; e < NEXP; ++e) if (bi[e] > b1) { b1 = bi[e]; i1 = e; }
        int i2 = -1; float b2 = -1e30f;
        for (int e = 0; e < NEXP; ++e) { if (e == i1) continue; if (bi[e] > b2) { b2 = bi[e]; i2 = e; } }
        float w1 = sc[i1], w2 = sc[i2];
        float s = w1 + w2;
        w1 /= s; w2 /= s;
        tok_e[t * 2]     = i1;  tok_e[t * 2 + 1] = i2;
        tok_w[t * 2]     = w1;  tok_w[t * 2 + 1] = w2;
        atomicAdd(&counts[i1], 1);
        atomicAdd(&counts[i2], 1);
    }
}

__global__ void k_zero(int* p) { if (threadIdx.x < 16) p[threadIdx.x] = 0; }

// serial scan + tile worklist (BM=64 tiles shared by gu and down kernels)
__global__ void k_scan(const int* __restrict__ counts, int* __restrict__ offs,
                       int* __restrict__ cursor, int* __restrict__ tiles, int* __restrict__ ntiles)
{
    if (threadIdx.x == 0) {
        int s = 0, nt = 0;
        for (int e = 0; e < NEXP; ++e) {
            offs[e] = s; cursor[e] = s;
            int c = counts[e];
            for (int mt = 0; mt * 64 < c; ++mt) tiles[nt++] = (e << 8) | mt;
            s += c;
        }
        offs[NEXP] = s; *ntiles = nt;
    }
}

__global__ void k_scatter(const int* __restrict__ tok_e, const float* __restrict__ tok_w,
                          int* __restrict__ cursor, int* __restrict__ row_token, float* __restrict__ row_w)
{
    int p = blockIdx.x * blockDim.x + threadIdx.x;
    if (p >= NPAIR) return;
    int e = tok_e[p];
    int pos = atomicAdd(&cursor[e], 1);
    row_token[pos] = p >> 1;
    row_w[pos] = tok_w[p];
}

__global__ __launch_bounds__(256) void k_cast_x(const float* __restrict__ x, bf16* __restrict__ xb)
{
    int i = (blockIdx.x * 256 + threadIdx.x) * 4;
    float4 v = *(const float4*)(x + i);
    bf16x4 o = { (bf16)v.x, (bf16)v.y, (bf16)v.z, (bf16)v.w };
    *(bf16x4*)(xb + i) = o;
}

// ---------------- routed gate_up + SwiGLU (MFMA) ----------------
// BM=64 grouped rows, BN=32 gate cols + matching 32 up cols, BK=64, K=1024
// grid: x = 16 (I/32), y = 48 (tile worklist)
__global__ __launch_bounds__(256) void k_moe_gu(
    const bf16* __restrict__ xb, const float* __restrict__ wgu,
    const int* __restrict__ offs, const int* __restrict__ row_token,
    const int* __restrict__ tiles, const int* __restrict__ ntiles,
    bf16* __restrict__ act)
{
    int ty = blockIdx.y;
    if (ty >= *ntiles) return;
    int tile = tiles[ty];
    int e = tile >> 8, mt = tile & 255;
    int m0 = offs[e] + mt * 64;
    int mcnt = min(64, offs[e + 1] - m0);
    int n0 = blockIdx.x * 32;

    __shared__ bf16 As[64][72];
    __shared__ bf16 Bg[32][72];
    __shared__ bf16 Bu[32][72];
    __shared__ int  toks[64];

    int tid = threadIdx.x;
    if (tid < 64) toks[tid] = row_token[m0 + min(tid, mcnt - 1)];
    __syncthreads();

    int ar0 = tid >> 3, akc = (tid & 7) * 8;
    int ar1 = (tid + 256) >> 3;
    const bf16* a_src0 = xb + (size_t)toks[ar0] * H_DIM + akc;
    const bf16* a_src1 = xb + (size_t)toks[ar1] * H_DIM + akc;
    int br = tid >> 3, bkc = (tid & 7) * 8;
    const float* wge = wgu + (size_t)e * (2 * I_DIM) * H_DIM;
    const float* g_src = wge + (size_t)(n0 + br) * H_DIM + bkc;
    const float* u_src = wge + (size_t)(I_DIM + n0 + br) * H_DIM + bkc;

    int lane = tid & 63, w = tid >> 6;
    int wm = w >> 1, wn = w & 1;
    int lr = lane & 15, lk8 = (lane >> 4) * 8;

    f32x4 aG[2] = {{0,0,0,0},{0,0,0,0}};
    f32x4 aU[2] = {{0,0,0,0},{0,0,0,0}};

    for (int k0 = 0; k0 < H_DIM; k0 += 64) {
        bf16x8 va0 = *(const bf16x8*)(a_src0 + k0);
        bf16x8 va1 = *(const bf16x8*)(a_src1 + k0);
        float4 g0 = *(const float4*)(g_src + k0);
        float4 g1 = *(const float4*)(g_src + k0 + 4);
        float4 u0 = *(const float4*)(u_src + k0);
        float4 u1 = *(const float4*)(u_src + k0 + 4);
        *(bf16x8*)&As[ar0][akc] = va0;
        *(bf16x8*)&As[ar1][akc] = va1;
        bf16x8 bg8 = { (bf16)g0.x,(bf16)g0.y,(bf16)g0.z,(bf16)g0.w,
                       (bf16)g1.x,(bf16)g1.y,(bf16)g1.z,(bf16)g1.w };
        bf16x8 bu8 = { (bf16)u0.x,(bf16)u0.y,(bf16)u0.z,(bf16)u0.w,
                       (bf16)u1.x,(bf16)u1.y,(bf16)u1.z,(bf16)u1.w };
        *(bf16x8*)&Bg[br][bkc] = bg8;
        *(bf16x8*)&Bu[br][bkc] = bu8;
        __syncthreads();
        #pragma unroll
        for (int ks = 0; ks < 2; ++ks) {
            bf16x8 a0 = *(const bf16x8*)&As[wm * 32 + lr][ks * 32 + lk8];
            bf16x8 a1 = *(const bf16x8*)&As[wm * 32 + 16 + lr][ks * 32 + lk8];
            bf16x8 bg = *(const bf16x8*)&Bg[wn * 16 + lr][ks * 32 + lk8];
            bf16x8 bu = *(const bf16x8*)&Bu[wn * 16 + lr][ks * 32 + lk8];
            aG[0] = MFMA(a0, bg, aG[0]);
            aG[1] = MFMA(a1, bg, aG[1]);
            aU[0] = MFMA(a0, bu, aU[0]);
            aU[1] = MFMA(a1, bu, aU[1]);
        }
        __syncthreads();
    }

    #pragma unroll
    for (int mf = 0; mf < 2; ++mf) {
        #pragma unroll
        for (int j = 0; j < 4; ++j) {
            int rl = wm * 32 + mf * 16 + (lane >> 4) * 4 + j;
            if (rl < mcnt) {
                float g = aG[mf][j], u = aU[mf][j];
                float v = (g / (1.f + __expf(-g))) * u;
                act[(size_t)(m0 + rl) * I_DIM + n0 + wn * 16 + lr] = (bf16)v;
            }
        }
    }
}

// ---------------- shared gate_up + SwiGLU (MFMA) ----------------
// BM=64, BN=32 gate + 32 up, K=1024; grid: x=32 (ISH/32), y=16 (T/64)
__global__ __launch_bounds__(256) void k_sh_gu(
    const bf16* __restrict__ xb, const float* __restrict__ sgu, bf16* __restrict__ act2)
{
    int m0 = blockIdx.y * 64;
    int n0 = blockIdx.x * 32;

    __shared__ bf16 As[64][72];
    __shared__ bf16 Bg[32][72];
    __shared__ bf16 Bu[32][72];

    int tid = threadIdx.x;
    int ar0 = tid >> 3, akc = (tid & 7) * 8;
    int ar1 = (tid + 256) >> 3;
    const bf16* a_src0 = xb + (size_t)(m0 + ar0) * H_DIM + akc;
    const bf16* a_src1 = xb + (size_t)(m0 + ar1) * H_DIM + akc;
    int br = tid >> 3, bkc = (tid & 7) * 8;
    const float* g_src = sgu + (size_t)(n0 + br) * H_DIM + bkc;
    const float* u_src = sgu + (size_t)(ISH + n0 + br) * H_DIM + bkc;

    int lane = tid & 63, w = tid >> 6;
    int wm = w >> 1, wn = w & 1;
    int lr = lane & 15, lk8 = (lane >> 4) * 8;

    f32x4 aG[2] = {{0,0,0,0},{0,0,0,0}};
    f32x4 aU[2] = {{0,0,0,0},{0,0,0,0}};

    for (int k0 = 0; k0 < H_DIM; k0 += 64) {
        bf16x8 va0 = *(const bf16x8*)(a_src0 + k0);
        bf16x8 va1 = *(const bf16x8*)(a_src1 + k0);
        float4 g0 = *(const float4*)(g_src + k0);
        float4 g1 = *(const float4*)(g_src + k0 + 4);
        float4 u0 = *(const float4*)(u_src + k0);
        float4 u1 = *(const float4*)(u_src + k0 + 4);
        *(bf16x8*)&As[ar0][akc] = va0;
        *(bf16x8*)&As[ar1][akc] = va1;
        bf16x8 bg8 = { (bf16)g0.x,(bf16)g0.y,(bf16)g0.z,(bf16)g0.w,
                       (bf16)g1.x,(bf16)g1.y,(bf16)g1.z,(bf16)g1.w };
        bf16x8 bu8 = { (bf16)u0.x,(bf16)u0.y,(bf16)u0.z,(bf16)u0.w,
                       (bf16)u1.x,(bf16)u1.y,(bf16)u1.z,(bf16)u1.w };
        *(bf16x8*)&Bg[br][bkc] = bg8;
        *(bf16x8*)&Bu[br][bkc] = bu8;
        __syncthreads();
        #pragma unroll
        for (int ks = 0; ks < 2; ++ks) {
            bf16x8 a0 = *(const bf16x8*)&As[wm * 32 + lr][ks * 32 + lk8];
            bf16x8 a1 = *(const bf16x8*)&As[wm * 32 + 16 + lr][ks * 32 + lk8];
            bf16x8 bg = *(const bf16x8*)&Bg[wn * 16 + lr][ks * 32 + lk8];
            bf16x8 bu = *(const bf16x8*)&Bu[wn * 16 + lr][ks * 32 + lk8];
            aG[0] = MFMA(a0, bg, aG[0]);
            aG[1] = MFMA(a1, bg, aG[1]);
            aU[0] = MFMA(a0, bu, aU[0]);
            aU[1] = MFMA(a1, bu, aU[1]);
        }
        __syncthreads();
    }

    #pragma unroll
    for (int mf = 0; mf < 2; ++mf) {
        #pragma unroll
        for (int j = 0; j < 4; ++j) {
            int rl = wm * 32 + mf * 16 + (lane >> 4) * 4 + j;
            float g = aG[mf][j], u = aU[mf][j];
            float v = (g / (1.f + __expf(-g))) * u;
            act2[(size_t)(m0 + rl) * ISH + n0 + wn * 16 + lr] = (bf16)v;
        }
    }
}

// ---------------- shared down (MFMA): writes out ----------------
// BM=64, BN=32, K=1024; grid: x=32 (H/32), y=16
__global__ __launch_bounds__(256) void k_sh_down(
    const bf16* __restrict__ act2, const float* __restrict__ sd, float* __restrict__ out)
{
    int m0 = blockIdx.y * 64;
    int n0 = blockIdx.x * 32;

    __shared__ bf16 As[64][72];
    __shared__ bf16 Bs[32][72];

    int tid = threadIdx.x;
    int ar0 = tid >> 3, akc = (tid & 7) * 8;
    int ar1 = (tid + 256) >> 3;
    const bf16* a_src0 = act2 + (size_t)(m0 + ar0) * ISH + akc;
    const bf16* a_src1 = act2 + (size_t)(m0 + ar1) * ISH + akc;
    int br = tid >> 3, bkc = (tid & 7) * 8;
    const float* b_src = sd + (size_t)(n0 + br) * ISH + bkc;

    int lane = tid & 63, w = tid >> 6;
    int wm = w >> 1, wn = w & 1;
    int lr = lane & 15, lk8 = (lane >> 4) * 8;

    f32x4 acc[2] = {{0,0,0,0},{0,0,0,0}};

    for (int k0 = 0; k0 < ISH; k0 += 64) {
        bf16x8 va0 = *(const bf16x8*)(a_src0 + k0);
        bf16x8 va1 = *(const bf16x8*)(a_src1 + k0);
        float4 b0 = *(const float4*)(b_src + k0);
        float4 b1 = *(const float4*)(b_src + k0 + 4);
        *(bf16x8*)&As[ar0][akc] = va0;
        *(bf16x8*)&As[ar1][akc] = va1;
        bf16x8 bb8 = { (bf16)b0.x,(bf16)b0.y,(bf16)b0.z,(bf16)b0.w,
                       (bf16)b1.x,(bf16)b1.y,(bf16)b1.z,(bf16)b1.w };
        *(bf16x8*)&Bs[br][bkc] = bb8;
        __syncthreads();
        #pragma unroll
        for (int ks = 0; ks < 2; ++ks) {
            bf16x8 a0 = *(const bf16x8*)&As[wm * 32 + lr][ks * 32 + lk8];
            bf16x8 a1 = *(const bf16x8*)&As[wm * 32 + 16 + lr][ks * 32 + lk8];
            bf16x8 bb = *(const bf16x8*)&Bs[wn * 16 + lr][ks * 32 + lk8];
            acc[0] = MFMA(a0, bb, acc[0]);
            acc[1] = MFMA(a1, bb, acc[1]);
        }
        __syncthreads();
    }

    #pragma unroll
    for (int mf = 0; mf < 2; ++mf) {
        #pragma unroll
        for (int j = 0; j < 4; ++j) {
            int rl = wm * 32 + mf * 16 + (lane >> 4) * 4 + j;
            out[(size_t)(m0 + rl) * H_DIM + n0 + wn * 16 + lr] = acc[mf][j];
        }
    }
}

// ---------------- routed down + weighted atomic combine (MFMA) ----------------
// BM=64, BN=64, K=512; grid: x=16 (H/64), y=48 (tile worklist)
__global__ __launch_bounds__(256) void k_moe_down(
    const bf16* __restrict__ act, const float* __restrict__ wd,
    const int* __restrict__ offs, const int* __restrict__ row_token,
    const float* __restrict__ row_w, const int* __restrict__ tiles,
    const int* __restrict__ ntiles, float* __restrict__ out)
{
    int ty = blockIdx.y;
    if (ty >= *ntiles) return;
    int tile = tiles[ty];
    int e = tile >> 8, mt = tile & 255;
    int m0 = offs[e] + mt * 64;
    int mcnt = min(64, offs[e + 1] - m0);
    int n0 = blockIdx.x * 64;

    __shared__ bf16 As[64][72];
    __shared__ bf16 Bs[64][72];

    int tid = threadIdx.x;
    int ar0 = tid >> 3, akc = (tid & 7) * 8;
    int ar1 = (tid + 256) >> 3;
    const bf16* a_src0 = act + (size_t)(m0 + min(ar0, mcnt - 1)) * I_DIM + akc;
    const bf16* a_src1 = act + (size_t)(m0 + min(ar1, mcnt - 1)) * I_DIM + akc;
    int br = tid >> 2, bkc = (tid & 3) * 16;
    const float* b_src = wd + (size_t)e * H_DIM * I_DIM + (size_t)(n0 + br) * I_DIM + bkc;

    int lane = tid & 63, w = tid >> 6;
    int wm = w >> 1, wn = w & 1;
    int lr = lane & 15, lk8 = (lane >> 4) * 8;

    f32x4 acc[2][2] = {{{0,0,0,0},{0,0,0,0}},{{0,0,0,0},{0,0,0,0}}};

    for (int k0 = 0; k0 < I_DIM; k0 += 64) {
        bf16x8 va0 = *(const bf16x8*)(a_src0 + k0);
        bf16x8 va1 = *(const bf16x8*)(a_src1 + k0);
        float4 b0 = *(const float4*)(b_src + k0);
        float4 b1 = *(const float4*)(b_src + k0 + 4);
        float4 b2 = *(const float4*)(b_src + k0 + 8);
        float4 b3 = *(const float4*)(b_src + k0 + 12);
        *(bf16x8*)&As[ar0][akc] = va0;
        *(bf16x8*)&As[ar1][akc] = va1;
        bf16x8 w0 = { (bf16)b0.x,(bf16)b0.y,(bf16)b0.z,(bf16)b0.w,
                      (bf16)b1.x,(bf16)b1.y,(bf16)b1.z,(bf16)b1.w };
        bf16x8 w1 = { (bf16)b2.x,(bf16)b2.y,(bf16)b2.z,(bf16)b2.w,
                      (bf16)b3.x,(bf16)b3.y,(bf16)b3.z,(bf16)b3.w };
        *(bf16x8*)&Bs[br][bkc] = w0;
        *(bf16x8*)&Bs[br][bkc + 8] = w1;
        __syncthreads();
        #pragma unroll
        for (int ks = 0; ks < 2; ++ks) {
            bf16x8 a0 = *(const bf16x8*)&As[wm * 32 + lr][ks * 32 + lk8];
            bf16x8 a1 = *(const bf16x8*)&As[wm * 32 + 16 + lr][ks * 32 + lk8];
            bf16x8 bb0 = *(const bf16x8*)&Bs[wn * 32 + lr][ks * 32 + lk8];
            bf16x8 bb1 = *(const bf16x8*)&Bs[wn * 32 + 16 + lr][ks * 32 + lk8];
            acc[0][0] = MFMA(a0, bb0, acc[0][0]);
            acc[0][1] = MFMA(a0, bb1, acc[0][1]);
            acc[1][0] = MFMA(a1, bb0, acc[1][0]);
            acc[1][1] = MFMA(a1, bb1, acc[1][1]);
        }
        __syncthreads();
    }

    #pragma unroll
    for (int mf = 0; mf < 2; ++mf) {
        #pragma unroll
        for (int j = 0; j < 4; ++j) {
            int rl = wm * 32 + mf * 16 + (lane >> 4) * 4 + j;
            if (rl < mcnt) {
                int t = row_token[m0 + rl];
                float wt = row_w[m0 + rl];
                #pragma unroll
                for (int nf = 0; nf < 2; ++nf) {
                    atomicAdd(&out[(size_t)t * H_DIM + n0 + wn * 32 + nf * 16 + lr],
                              wt * acc[mf][nf][j]);
                }
            }
        }
    }
}

extern "C" void kernel_launch(void* const* d_in, const int* in_sizes, int n_in,
                              void* d_out, int out_size, void* d_ws, size_t ws_size,
                              hipStream_t stream)
{
    (void)in_sizes; (void)n_in; (void)out_size; (void)ws_size;
    const float* x    = (const float*)d_in[0];
    const float* gw   = (const float*)d_in[1];
    const float* bias = (const float*)d_in[2];
    const float* wgu  = (const float*)d_in[3];
    const float* wd   = (const float*)d_in[4];
    const float* sgu  = (const float*)d_in[5];
    const float* sd   = (const float*)d_in[6];
    float* out = (float*)d_out;

    char* ws = (char*)d_ws;
    int*   counts    = (int*)(ws);
    int*   cursor    = (int*)(ws + 64);
    int*   offs      = (int*)(ws + 128);
    int*   ntiles    = (int*)(ws + 256);
    int*   tiles     = (int*)(ws + 320);
    int*   tok_e     = (int*)(ws + 1024);
    float* tok_w     = (float*)(ws + 9216);
    int*   row_token = (int*)(ws + 17408);
    float* row_w     = (float*)(ws + 25600);
    bf16*  xb        = (bf16*)(ws + 40960);
    bf16*  act       = (bf16*)(ws + 40960 + 2097152);
    bf16*  act2      = (bf16*)(ws + 40960 + 2 * 2097152);

    k_zero<<<1, 64, 0, stream>>>(counts);
    k_cast_x<<<1024, 256, 0, stream>>>(x, xb);
    k_router<<<T_TOK, 64, 0, stream>>>(x, gw, bias, tok_e, tok_w, counts);
    k_scan<<<1, 64, 0, stream>>>(counts, offs, cursor, tiles, ntiles);
    k_scatter<<<NPAIR / 256, 256, 0, stream>>>(tok_e, tok_w, cursor, row_token, row_w);
    k_moe_gu<<<dim3(16, 48), 256, 0, stream>>>(xb, wgu, offs, row_token, tiles, ntiles, act);
    k_sh_gu<<<dim3(32, 16), 256, 0, stream>>>(xb, sgu, act2);
    k_sh_down<<<dim3(32, 16), 256, 0, stream>>>(act2, sd, out);
    k_moe_down<<<dim3(16, 48), 256, 0, stream>>>(act, wd, offs, row_token, row_w, tiles, ntiles, out);
}

// Round 3
// 111.162 us; speedup vs baseline: 4.4324x; 1.0883x over previous
//
#include <hip/hip_runtime.h>
#include <math.h>

#define T_TOK 1024
#define H_DIM 1024
#define NEXP  16
#define I_DIM 512
#define ISH   1024

typedef __bf16 bf16;
typedef __bf16 bf16x4 __attribute__((ext_vector_type(4)));
typedef __bf16 bf16x8 __attribute__((ext_vector_type(8)));
typedef float  f32x4  __attribute__((ext_vector_type(4)));

#define MFMA(a,b,c) __builtin_amdgcn_mfma_f32_16x16x32_bf16(a,b,c,0,0,0)

// ---------------- cast x -> bf16 ----------------
__global__ __launch_bounds__(256) void k_cast_x(const float* __restrict__ x, bf16* __restrict__ xb)
{
    int i = (blockIdx.x * 256 + threadIdx.x) * 4;
    float4 v = *(const float4*)(x + i);
    bf16x4 o = { (bf16)v.x, (bf16)v.y, (bf16)v.z, (bf16)v.w };
    *(bf16x4*)(xb + i) = o;
}

// ---------------- router: 4 tokens/block, 1 wave/token, float4 loads ----------------
__global__ __launch_bounds__(256) void k_router(const float* __restrict__ x,
        const float* __restrict__ gw, const float* __restrict__ bias,
        int* __restrict__ tok_e, float* __restrict__ tok_w)
{
    int t = blockIdx.x * 4 + (threadIdx.x >> 6);
    int lane = threadIdx.x & 63;
    const float* xrow = x + (size_t)t * H_DIM + lane * 16;
    float acc[NEXP];
    #pragma unroll
    for (int e = 0; e < NEXP; ++e) acc[e] = 0.f;
    #pragma unroll
    for (int kc = 0; kc < 4; ++kc) {
        float4 xv = *(const float4*)(xrow + kc * 4);
        const float* gp = gw + lane * 16 + kc * 4;
        #pragma unroll
        for (int e = 0; e < NEXP; ++e) {
            float4 wv = *(const float4*)(gp + e * H_DIM);
            acc[e] += xv.x * wv.x + xv.y * wv.y + xv.z * wv.z + xv.w * wv.w;
        }
    }
    #pragma unroll
    for (int e = 0; e < NEXP; ++e) {
        float v = acc[e];
        #pragma unroll
        for (int off = 1; off < 64; off <<= 1) v += __shfl_xor(v, off);
        acc[e] = v;
    }
    if (lane == 0) {
        float sc[NEXP], bi[NEXP];
        #pragma unroll
        for (int e = 0; e < NEXP; ++e) {
            sc[e] = 1.f / (1.f + expf(-acc[e]));
            bi[e] = sc[e] + bias[e];
        }
        int i1 = 0; float b1 = bi[0];
        for (int e = 1; e < NEXP; ++e) if (bi[e] > b1) { b1 = bi[e]; i1 = e; }
        int i2 = -1; float b2 = -1e30f;
        for (int e = 0; e < NEXP; ++e) { if (e == i1) continue; if (bi[e] > b2) { b2 = bi[e]; i2 = e; } }
        float w1 = sc[i1], w2 = sc[i2];
        float s = w1 + w2;
        w1 /= s; w2 /= s;
        tok_e[t * 2]     = i1;  tok_e[t * 2 + 1] = i2;
        tok_w[t * 2]     = w1;  tok_w[t * 2 + 1] = w2;
    }
}

// ---------------- build: histogram + scan + tiles + scatter (one block) ----------------
__global__ __launch_bounds__(256) void k_build(const int* __restrict__ tok_e,
        const float* __restrict__ tok_w, int* __restrict__ offs_g,
        int* __restrict__ tiles, int* __restrict__ ntiles,
        int* __restrict__ row_token, float* __restrict__ row_w)
{
    __shared__ int cnt[NEXP], cur[NEXP];
    int tid = threadIdx.x;
    if (tid < NEXP) cnt[tid] = 0;
    __syncthreads();
    for (int p = tid; p < 2 * T_TOK; p += 256) atomicAdd(&cnt[tok_e[p]], 1);
    __syncthreads();
    if (tid == 0) {
        int s = 0, nt = 0;
        for (int e = 0; e < NEXP; ++e) {
            offs_g[e] = s; cur[e] = s;
            int c = cnt[e];
            for (int mt = 0; mt * 64 < c; ++mt) tiles[nt++] = (e << 8) | mt;
            s += c;
        }
        offs_g[NEXP] = s; *ntiles = nt;
    }
    __syncthreads();
    for (int p = tid; p < 2 * T_TOK; p += 256) {
        int e = tok_e[p];
        int pos = atomicAdd(&cur[e], 1);
        row_token[pos] = p >> 1;
        row_w[pos] = tok_w[p];
    }
}

// ---------------- gate_up + SwiGLU: BM=64, BN=64(g)+64(u), BK=64 ----------------
template<bool GATHER>
__global__ __launch_bounds__(256) void k_gu(
    const bf16* __restrict__ xb, const float* __restrict__ W,
    bf16* __restrict__ act, int gup_off,
    const int* __restrict__ offs, const int* __restrict__ row_token,
    const int* __restrict__ tiles, const int* __restrict__ ntiles)
{
    int m0, mcnt, e = 0;
    if constexpr (GATHER) {
        int ty = blockIdx.y;
        if (ty >= *ntiles) return;
        int tile = tiles[ty]; e = tile >> 8; int mt = tile & 255;
        m0 = offs[e] + mt * 64; mcnt = min(64, offs[e + 1] - m0);
    } else { m0 = blockIdx.y * 64; mcnt = 64; }
    int n0 = blockIdx.x * 64;

    __shared__ bf16 As[64][72];
    __shared__ bf16 Bg[64][72];
    __shared__ bf16 Bu[64][72];
    __shared__ int  toks[64];

    int tid = threadIdx.x;
    if constexpr (GATHER) {
        if (tid < 64) toks[tid] = row_token[m0 + min(tid, mcnt - 1)];
        __syncthreads();
    }

    const float* Wb = W + (GATHER ? (size_t)e * (2 * (size_t)I_DIM * H_DIM) : 0);
    const float* gbase = Wb + (size_t)n0 * H_DIM;
    const float* ubase = Wb + (size_t)(gup_off + n0) * H_DIM;

    int lane = tid & 63, w = tid >> 6, wm = w >> 1, wn = w & 1;
    int lr = lane & 15, lk8 = (lane >> 4) * 8;

    f32x4 aG[2][2], aU[2][2];
    #pragma unroll
    for (int i = 0; i < 2; ++i)
        #pragma unroll
        for (int j = 0; j < 2; ++j) { aG[i][j] = (f32x4){0,0,0,0}; aU[i][j] = (f32x4){0,0,0,0}; }

    int r0 = tid >> 3, c8 = (tid & 7) * 8;
    int r1 = r0 + 32;
    int arow0, arow1;
    if constexpr (GATHER) { arow0 = toks[r0]; arow1 = toks[r1]; }
    else { arow0 = m0 + r0; arow1 = m0 + r1; }
    const bf16* a_src0 = xb + (size_t)arow0 * H_DIM + c8;
    const bf16* a_src1 = xb + (size_t)arow1 * H_DIM + c8;

    for (int k0 = 0; k0 < H_DIM; k0 += 64) {
        bf16x8 a0 = *(const bf16x8*)(a_src0 + k0);
        bf16x8 a1 = *(const bf16x8*)(a_src1 + k0);
        *(bf16x8*)&As[r0][c8] = a0;
        *(bf16x8*)&As[r1][c8] = a1;
        #pragma unroll
        for (int s = 0; s < 2; ++s) {
            int r = r0 + s * 32;
            const float* pg = gbase + (size_t)r * H_DIM + k0 + c8;
            const float* pu = ubase + (size_t)r * H_DIM + k0 + c8;
            float4 g0 = *(const float4*)pg, g1 = *(const float4*)(pg + 4);
            float4 u0 = *(const float4*)pu, u1 = *(const float4*)(pu + 4);
            bf16x8 gg = { (bf16)g0.x,(bf16)g0.y,(bf16)g0.z,(bf16)g0.w,
                          (bf16)g1.x,(bf16)g1.y,(bf16)g1.z,(bf16)g1.w };
            bf16x8 uu = { (bf16)u0.x,(bf16)u0.y,(bf16)u0.z,(bf16)u0.w,
                          (bf16)u1.x,(bf16)u1.y,(bf16)u1.z,(bf16)u1.w };
            *(bf16x8*)&Bg[r][c8] = gg;
            *(bf16x8*)&Bu[r][c8] = uu;
        }
        __syncthreads();
        #pragma unroll
        for (int ks = 0; ks < 2; ++ks) {
            bf16x8 fa0 = *(const bf16x8*)&As[wm * 32 + lr][ks * 32 + lk8];
            bf16x8 fa1 = *(const bf16x8*)&As[wm * 32 + 16 + lr][ks * 32 + lk8];
            bf16x8 fg0 = *(const bf16x8*)&Bg[wn * 32 + lr][ks * 32 + lk8];
            bf16x8 fg1 = *(const bf16x8*)&Bg[wn * 32 + 16 + lr][ks * 32 + lk8];
            bf16x8 fu0 = *(const bf16x8*)&Bu[wn * 32 + lr][ks * 32 + lk8];
            bf16x8 fu1 = *(const bf16x8*)&Bu[wn * 32 + 16 + lr][ks * 32 + lk8];
            aG[0][0] = MFMA(fa0, fg0, aG[0][0]);
            aG[0][1] = MFMA(fa0, fg1, aG[0][1]);
            aG[1][0] = MFMA(fa1, fg0, aG[1][0]);
            aG[1][1] = MFMA(fa1, fg1, aG[1][1]);
            aU[0][0] = MFMA(fa0, fu0, aU[0][0]);
            aU[0][1] = MFMA(fa0, fu1, aU[0][1]);
            aU[1][0] = MFMA(fa1, fu0, aU[1][0]);
            aU[1][1] = MFMA(fa1, fu1, aU[1][1]);
        }
        __syncthreads();
    }

    #pragma unroll
    for (int mi = 0; mi < 2; ++mi) {
        #pragma unroll
        for (int j = 0; j < 4; ++j) {
            int rl = wm * 32 + mi * 16 + (lane >> 4) * 4 + j;
            if (!GATHER || rl < mcnt) {
                #pragma unroll
                for (int ni = 0; ni < 2; ++ni) {
                    float g = aG[mi][ni][j], u = aU[mi][ni][j];
                    float v = (g / (1.f + __expf(-g))) * u;
                    act[(size_t)(m0 + rl) * gup_off + n0 + wn * 32 + ni * 16 + lr] = (bf16)v;
                }
            }
        }
    }
}

// ---------------- down proj: BM=64, BN=64, BK=64 ----------------
template<bool GATHER>
__global__ __launch_bounds__(256) void k_down(
    const bf16* __restrict__ A, const float* __restrict__ W,
    float* __restrict__ out, int K,
    const int* __restrict__ offs, const int* __restrict__ row_token,
    const float* __restrict__ row_w,
    const int* __restrict__ tiles, const int* __restrict__ ntiles)
{
    int m0, mcnt, e = 0;
    if constexpr (GATHER) {
        int ty = blockIdx.y;
        if (ty >= *ntiles) return;
        int tile = tiles[ty]; e = tile >> 8; int mt = tile & 255;
        m0 = offs[e] + mt * 64; mcnt = min(64, offs[e + 1] - m0);
    } else { m0 = blockIdx.y * 64; mcnt = 64; }
    int n0 = blockIdx.x * 64;

    __shared__ bf16 As[64][72];
    __shared__ bf16 Bs[64][72];

    int tid = threadIdx.x;
    const float* Wb = W + (GATHER ? (size_t)e * H_DIM * I_DIM : 0) + (size_t)n0 * K;

    int lane = tid & 63, w = tid >> 6, wm = w >> 1, wn = w & 1;
    int lr = lane & 15, lk8 = (lane >> 4) * 8;

    f32x4 acc[2][2];
    #pragma unroll
    for (int i = 0; i < 2; ++i)
        #pragma unroll
        for (int j = 0; j < 2; ++j) acc[i][j] = (f32x4){0,0,0,0};

    int r0 = tid >> 3, c8 = (tid & 7) * 8;
    int r1 = r0 + 32;
    int arow0 = m0 + (GATHER ? min(r0, mcnt - 1) : r0);
    int arow1 = m0 + (GATHER ? min(r1, mcnt - 1) : r1);
    const bf16* a_src0 = A + (size_t)arow0 * K + c8;
    const bf16* a_src1 = A + (size_t)arow1 * K + c8;

    for (int k0 = 0; k0 < K; k0 += 64) {
        bf16x8 a0 = *(const bf16x8*)(a_src0 + k0);
        bf16x8 a1 = *(const bf16x8*)(a_src1 + k0);
        *(bf16x8*)&As[r0][c8] = a0;
        *(bf16x8*)&As[r1][c8] = a1;
        #pragma unroll
        for (int s = 0; s < 2; ++s) {
            int r = r0 + s * 32;
            const float* pb = Wb + (size_t)r * K + k0 + c8;
            float4 b0 = *(const float4*)pb, b1 = *(const float4*)(pb + 4);
            bf16x8 bb = { (bf16)b0.x,(bf16)b0.y,(bf16)b0.z,(bf16)b0.w,
                          (bf16)b1.x,(bf16)b1.y,(bf16)b1.z,(bf16)b1.w };
            *(bf16x8*)&Bs[r][c8] = bb;
        }
        __syncthreads();
        #pragma unroll
        for (int ks = 0; ks < 2; ++ks) {
            bf16x8 fa0 = *(const bf16x8*)&As[wm * 32 + lr][ks * 32 + lk8];
            bf16x8 fa1 = *(const bf16x8*)&As[wm * 32 + 16 + lr][ks * 32 + lk8];
            bf16x8 fb0 = *(const bf16x8*)&Bs[wn * 32 + lr][ks * 32 + lk8];
            bf16x8 fb1 = *(const bf16x8*)&Bs[wn * 32 + 16 + lr][ks * 32 + lk8];
            acc[0][0] = MFMA(fa0, fb0, acc[0][0]);
            acc[0][1] = MFMA(fa0, fb1, acc[0][1]);
            acc[1][0] = MFMA(fa1, fb0, acc[1][0]);
            acc[1][1] = MFMA(fa1, fb1, acc[1][1]);
        }
        __syncthreads();
    }

    #pragma unroll
    for (int mi = 0; mi < 2; ++mi) {
        #pragma unroll
        for (int j = 0; j < 4; ++j) {
            int rl = wm * 32 + mi * 16 + (lane >> 4) * 4 + j;
            if constexpr (GATHER) {
                if (rl < mcnt) {
                    int t = row_token[m0 + rl];
                    float wt = row_w[m0 + rl];
                    #pragma unroll
                    for (int ni = 0; ni < 2; ++ni)
                        atomicAdd(&out[(size_t)t * H_DIM + n0 + wn * 32 + ni * 16 + lr],
                                  wt * acc[mi][ni][j]);
                }
            } else {
                #pragma unroll
                for (int ni = 0; ni < 2; ++ni)
                    out[(size_t)(m0 + rl) * H_DIM + n0 + wn * 32 + ni * 16 + lr] = acc[mi][ni][j];
            }
        }
    }
}

extern "C" void kernel_launch(void* const* d_in, const int* in_sizes, int n_in,
                              void* d_out, int out_size, void* d_ws, size_t ws_size,
                              hipStream_t stream)
{
    (void)in_sizes; (void)n_in; (void)out_size; (void)ws_size;
    const float* x    = (const float*)d_in[0];
    const float* gw   = (const float*)d_in[1];
    const float* bias = (const float*)d_in[2];
    const float* wgu  = (const float*)d_in[3];
    const float* wd   = (const float*)d_in[4];
    const float* sgu  = (const float*)d_in[5];
    const float* sd   = (const float*)d_in[6];
    float* out = (float*)d_out;

    char* ws = (char*)d_ws;
    int*   offs_g    = (int*)(ws);
    int*   ntiles    = (int*)(ws + 128);
    int*   tiles     = (int*)(ws + 256);
    int*   tok_e     = (int*)(ws + 4096);
    float* tok_w     = (float*)(ws + 16384);
    int*   row_token = (int*)(ws + 32768);
    float* row_w     = (float*)(ws + 49152);
    bf16*  xb        = (bf16*)(ws + 65536);
    bf16*  act       = (bf16*)(ws + 65536 + (1 << 21));
    bf16*  act2      = (bf16*)(ws + 65536 + (2 << 21));

    k_cast_x<<<T_TOK, 256, 0, stream>>>(x, xb);
    k_router<<<T_TOK / 4, 256, 0, stream>>>(x, gw, bias, tok_e, tok_w);
    k_build<<<1, 256, 0, stream>>>(tok_e, tok_w, offs_g, tiles, ntiles, row_token, row_w);
    k_gu<true><<<dim3(I_DIM / 64, 48), 256, 0, stream>>>(xb, wgu, act, I_DIM,
                                                         offs_g, row_token, tiles, ntiles);
    k_gu<false><<<dim3(ISH / 64, T_TOK / 64), 256, 0, stream>>>(xb, sgu, act2, ISH,
                                                                nullptr, nullptr, nullptr, nullptr);
    k_down<false><<<dim3(H_DIM / 64, T_TOK / 64), 256, 0, stream>>>(act2, sd, out, ISH,
                                                                    nullptr, nullptr, nullptr, nullptr, nullptr);
    k_down<true><<<dim3(H_DIM / 64, 48), 256, 0, stream>>>(act, wd, out, I_DIM,
                                                           offs_g, row_token, row_w, tiles, ntiles);
}

// Round 4
// 90.425 us; speedup vs baseline: 5.4489x; 1.2293x over previous
//
#include <hip/hip_runtime.h>
#include <math.h>

#define T_TOK 1024
#define H_DIM 1024
#define NEXP  16
#define I_DIM 512
#define ISH   1024
#define GU_GRID 640
#define DN_GRID 1280

typedef __bf16 bf16;
typedef __bf16 bf16x4 __attribute__((ext_vector_type(4)));
typedef __bf16 bf16x8 __attribute__((ext_vector_type(8)));
typedef float  f32x4  __attribute__((ext_vector_type(4)));

#define MFMA(a,b,c) __builtin_amdgcn_mfma_f32_16x16x32_bf16(a,b,c,0,0,0)

// ---------------- fused cast(x->bf16) + router: 4 tokens/block, 1 wave/token ----------------
__global__ __launch_bounds__(256) void k_cast_router(const float* __restrict__ x,
        const float* __restrict__ gw, const float* __restrict__ bias,
        bf16* __restrict__ xb, int* __restrict__ tok_e, float* __restrict__ tok_w)
{
    int t = blockIdx.x * 4 + (threadIdx.x >> 6);
    int lane = threadIdx.x & 63;
    const float* xrow = x + (size_t)t * H_DIM + lane * 16;
    bf16* xbrow = xb + (size_t)t * H_DIM + lane * 16;
    float acc[NEXP];
    #pragma unroll
    for (int e = 0; e < NEXP; ++e) acc[e] = 0.f;
    #pragma unroll
    for (int kc = 0; kc < 4; ++kc) {
        float4 xv = *(const float4*)(xrow + kc * 4);
        bf16x4 o = { (bf16)xv.x, (bf16)xv.y, (bf16)xv.z, (bf16)xv.w };
        *(bf16x4*)(xbrow + kc * 4) = o;
        const float* gp = gw + lane * 16 + kc * 4;
        #pragma unroll
        for (int e = 0; e < NEXP; ++e) {
            float4 wv = *(const float4*)(gp + e * H_DIM);
            acc[e] += xv.x * wv.x + xv.y * wv.y + xv.z * wv.z + xv.w * wv.w;
        }
    }
    #pragma unroll
    for (int e = 0; e < NEXP; ++e) {
        float v = acc[e];
        #pragma unroll
        for (int off = 1; off < 64; off <<= 1) v += __shfl_xor(v, off);
        acc[e] = v;
    }
    if (lane == 0) {
        float sc[NEXP], bi[NEXP];
        #pragma unroll
        for (int e = 0; e < NEXP; ++e) {
            sc[e] = 1.f / (1.f + expf(-acc[e]));
            bi[e] = sc[e] + bias[e];
        }
        int i1 = 0; float b1 = bi[0];
        for (int e = 1; e < NEXP; ++e) if (bi[e] > b1) { b1 = bi[e]; i1 = e; }
        int i2 = -1; float b2 = -1e30f;
        for (int e = 0; e < NEXP; ++e) { if (e == i1) continue; if (bi[e] > b2) { b2 = bi[e]; i2 = e; } }
        float w1 = sc[i1], w2 = sc[i2];
        float s = w1 + w2;
        w1 /= s; w2 /= s;
        tok_e[t * 2]     = i1;  tok_e[t * 2 + 1] = i2;
        tok_w[t * 2]     = w1;  tok_w[t * 2 + 1] = w2;
    }
}

// ---------------- build: histogram + scan + scatter + worklists (one block) ----------------
// gu entry  : routed: (e<<16)|(mt<<8)|nx          shared: (1<<30)|(mt<<8)|nx
// dn entry  : routed: (e<<16)|(mt<<8)|nx          shared: (1<<30)|(kh<<24)|(mt<<8)|nx
__global__ __launch_bounds__(256) void k_build(const int* __restrict__ tok_e,
        const float* __restrict__ tok_w, int* __restrict__ offs_g,
        int* __restrict__ row_token, float* __restrict__ row_w,
        int* __restrict__ wl_gu, int* __restrict__ n_gu,
        int* __restrict__ wl_dn, int* __restrict__ n_dn)
{
    __shared__ int cnt[NEXP], cur[NEXP], tcnt[NEXP], toff[NEXP + 1];
    int tid = threadIdx.x;
    if (tid < NEXP) cnt[tid] = 0;
    __syncthreads();
    for (int p = tid; p < 2 * T_TOK; p += 256) atomicAdd(&cnt[tok_e[p]], 1);
    __syncthreads();
    if (tid == 0) {
        int s = 0, ts = 0;
        for (int e = 0; e < NEXP; ++e) {
            offs_g[e] = s; cur[e] = s;
            int c = cnt[e];
            tcnt[e] = (c + 63) >> 6;
            toff[e] = ts;
            ts += tcnt[e];
            s += c;
        }
        offs_g[NEXP] = s; toff[NEXP] = ts;
        *n_gu = ts * 8 + 256;
        *n_dn = ts * 16 + 512;
    }
    __syncthreads();
    for (int p = tid; p < 2 * T_TOK; p += 256) {
        int e = tok_e[p];
        int pos = atomicAdd(&cur[e], 1);
        row_token[pos] = p >> 1;
        row_w[pos] = tok_w[p];
    }
    int ntr = toff[NEXP];
    // gate_up worklist: routed (e-major, nx outer, mt inner) then shared (nx outer, mt inner)
    int tot_gu = ntr * 8 + 256;
    for (int idx = tid; idx < tot_gu; idx += 256) {
        int entry;
        if (idx < ntr * 8) {
            int t8 = idx >> 3;
            int e = 0;
            while (!(t8 >= toff[e] && t8 < toff[e + 1])) ++e;
            int j = idx - 8 * toff[e];
            int nx = j / tcnt[e], mt = j % tcnt[e];
            entry = (e << 16) | (mt << 8) | nx;
        } else {
            int j = idx - ntr * 8;
            int nx = j >> 4, mt = j & 15;
            entry = (1 << 30) | (mt << 8) | nx;
        }
        wl_gu[idx] = entry;
    }
    // down worklist: routed (nx 0..15) then shared (nx outer, mt*2+kh inner)
    int tot_dn = ntr * 16 + 512;
    for (int idx = tid; idx < tot_dn; idx += 256) {
        int entry;
        if (idx < ntr * 16) {
            int t16 = idx >> 4;
            int e = 0;
            while (!(t16 >= toff[e] && t16 < toff[e + 1])) ++e;
            int j = idx - 16 * toff[e];
            int nx = j / tcnt[e], mt = j % tcnt[e];
            entry = (e << 16) | (mt << 8) | nx;
        } else {
            int j = idx - ntr * 16;
            int nx = j >> 5, r = j & 31;
            int mt = r >> 1, kh = r & 1;
            entry = (1 << 30) | (kh << 24) | (mt << 8) | nx;
        }
        wl_dn[idx] = entry;
    }
}

// ---------------- fused gate_up + SwiGLU (routed + shared): BM=64, BN=64g+64u, BK=64 ----------------
__global__ __launch_bounds__(256) void k_gu_all(
    const bf16* __restrict__ xb, const float* __restrict__ wgu, const float* __restrict__ sgu,
    bf16* __restrict__ act, bf16* __restrict__ act2,
    const int* __restrict__ offs, const int* __restrict__ row_token,
    const int* __restrict__ wl, const int* __restrict__ n_wl)
{
    int bid = blockIdx.x;
    int idx = (bid & 7) * (GU_GRID >> 3) + (bid >> 3);   // XCD-chunk swizzle
    if (idx >= *n_wl) return;
    int entry = wl[idx];
    bool sh = entry & (1 << 30);
    int mt = (entry >> 8) & 255, nx = entry & 255;
    int m0, mcnt, gup, e = 0;
    const float* W;
    bf16* dst;
    if (sh) { m0 = mt * 64; mcnt = 64; W = sgu; gup = ISH; dst = act2; }
    else {
        e = (entry >> 16) & 31;
        m0 = offs[e] + mt * 64; mcnt = min(64, offs[e + 1] - m0);
        W = wgu + (size_t)e * (2 * (size_t)I_DIM * H_DIM); gup = I_DIM; dst = act;
    }
    int n0 = nx * 64;

    __shared__ bf16 As[64][72];
    __shared__ bf16 Bg[64][72];
    __shared__ bf16 Bu[64][72];
    __shared__ int  toks[64];

    int tid = threadIdx.x;
    if (!sh) {
        if (tid < 64) toks[tid] = row_token[m0 + min(tid, mcnt - 1)];
        __syncthreads();
    }

    const float* gbase = W + (size_t)n0 * H_DIM;
    const float* ubase = W + (size_t)(gup + n0) * H_DIM;

    int lane = tid & 63, w = tid >> 6, wm = w >> 1, wn = w & 1;
    int lr = lane & 15, lk8 = (lane >> 4) * 8;

    f32x4 aG[2][2], aU[2][2];
    #pragma unroll
    for (int i = 0; i < 2; ++i)
        #pragma unroll
        for (int j = 0; j < 2; ++j) { aG[i][j] = (f32x4){0,0,0,0}; aU[i][j] = (f32x4){0,0,0,0}; }

    int r0 = tid >> 3, c8 = (tid & 7) * 8;
    int r1 = r0 + 32;
    int arow0, arow1;
    if (sh) { arow0 = m0 + r0; arow1 = m0 + r1; }
    else    { arow0 = toks[r0]; arow1 = toks[r1]; }
    const bf16* a_src0 = xb + (size_t)arow0 * H_DIM + c8;
    const bf16* a_src1 = xb + (size_t)arow1 * H_DIM + c8;

    for (int k0 = 0; k0 < H_DIM; k0 += 64) {
        bf16x8 a0 = *(const bf16x8*)(a_src0 + k0);
        bf16x8 a1 = *(const bf16x8*)(a_src1 + k0);
        *(bf16x8*)&As[r0][c8] = a0;
        *(bf16x8*)&As[r1][c8] = a1;
        #pragma unroll
        for (int s = 0; s < 2; ++s) {
            int r = r0 + s * 32;
            const float* pg = gbase + (size_t)r * H_DIM + k0 + c8;
            const float* pu = ubase + (size_t)r * H_DIM + k0 + c8;
            float4 g0 = *(const float4*)pg, g1 = *(const float4*)(pg + 4);
            float4 u0 = *(const float4*)pu, u1 = *(const float4*)(pu + 4);
            bf16x8 gg = { (bf16)g0.x,(bf16)g0.y,(bf16)g0.z,(bf16)g0.w,
                          (bf16)g1.x,(bf16)g1.y,(bf16)g1.z,(bf16)g1.w };
            bf16x8 uu = { (bf16)u0.x,(bf16)u0.y,(bf16)u0.z,(bf16)u0.w,
                          (bf16)u1.x,(bf16)u1.y,(bf16)u1.z,(bf16)u1.w };
            *(bf16x8*)&Bg[r][c8] = gg;
            *(bf16x8*)&Bu[r][c8] = uu;
        }
        __syncthreads();
        #pragma unroll
        for (int ks = 0; ks < 2; ++ks) {
            bf16x8 fa0 = *(const bf16x8*)&As[wm * 32 + lr][ks * 32 + lk8];
            bf16x8 fa1 = *(const bf16x8*)&As[wm * 32 + 16 + lr][ks * 32 + lk8];
            bf16x8 fg0 = *(const bf16x8*)&Bg[wn * 32 + lr][ks * 32 + lk8];
            bf16x8 fg1 = *(const bf16x8*)&Bg[wn * 32 + 16 + lr][ks * 32 + lk8];
            bf16x8 fu0 = *(const bf16x8*)&Bu[wn * 32 + lr][ks * 32 + lk8];
            bf16x8 fu1 = *(const bf16x8*)&Bu[wn * 32 + 16 + lr][ks * 32 + lk8];
            aG[0][0] = MFMA(fa0, fg0, aG[0][0]);
            aG[0][1] = MFMA(fa0, fg1, aG[0][1]);
            aG[1][0] = MFMA(fa1, fg0, aG[1][0]);
            aG[1][1] = MFMA(fa1, fg1, aG[1][1]);
            aU[0][0] = MFMA(fa0, fu0, aU[0][0]);
            aU[0][1] = MFMA(fa0, fu1, aU[0][1]);
            aU[1][0] = MFMA(fa1, fu0, aU[1][0]);
            aU[1][1] = MFMA(fa1, fu1, aU[1][1]);
        }
        __syncthreads();
    }

    #pragma unroll
    for (int mi = 0; mi < 2; ++mi) {
        #pragma unroll
        for (int j = 0; j < 4; ++j) {
            int rl = wm * 32 + mi * 16 + (lane >> 4) * 4 + j;
            if (rl < mcnt) {
                #pragma unroll
                for (int ni = 0; ni < 2; ++ni) {
                    float g = aG[mi][ni][j], u = aU[mi][ni][j];
                    float v = (g / (1.f + __expf(-g))) * u;
                    dst[(size_t)(m0 + rl) * gup + n0 + wn * 32 + ni * 16 + lr] = (bf16)v;
                }
            }
        }
    }
}

// ---------------- fused down (routed + shared, K-split on shared): BM=64, BN=64, K=512/block ----------------
__global__ __launch_bounds__(256) void k_dn_all(
    const bf16* __restrict__ act, const bf16* __restrict__ act2,
    const float* __restrict__ wd, const float* __restrict__ sd, float* __restrict__ out,
    const int* __restrict__ offs, const int* __restrict__ row_token, const float* __restrict__ row_w,
    const int* __restrict__ wl, const int* __restrict__ n_wl)
{
    int bid = blockIdx.x;
    int idx = (bid & 7) * (DN_GRID >> 3) + (bid >> 3);
    if (idx >= *n_wl) return;
    int entry = wl[idx];
    bool sh = entry & (1 << 30);
    int mt = (entry >> 8) & 255, nx = entry & 255;
    int m0, mcnt, kb, lda, ldw, e = 0;
    const bf16* A;
    const float* W;
    if (sh) {
        int kh = (entry >> 24) & 1;
        m0 = mt * 64; mcnt = 64; A = act2; lda = ISH; W = sd; ldw = ISH; kb = kh * 512;
    } else {
        e = (entry >> 16) & 31;
        m0 = offs[e] + mt * 64; mcnt = min(64, offs[e + 1] - m0);
        A = act; lda = I_DIM; W = wd + (size_t)e * H_DIM * I_DIM; ldw = I_DIM; kb = 0;
    }
    int n0 = nx * 64;

    __shared__ bf16 As[64][72];
    __shared__ bf16 Bs[64][72];

    int tid = threadIdx.x;
    int lane = tid & 63, w = tid >> 6, wm = w >> 1, wn = w & 1;
    int lr = lane & 15, lk8 = (lane >> 4) * 8;

    f32x4 acc[2][2];
    #pragma unroll
    for (int i = 0; i < 2; ++i)
        #pragma unroll
        for (int j = 0; j < 2; ++j) acc[i][j] = (f32x4){0,0,0,0};

    int r0 = tid >> 3, c8 = (tid & 7) * 8;
    int r1 = r0 + 32;
    int arow0 = m0 + (sh ? r0 : min(r0, mcnt - 1));
    int arow1 = m0 + (sh ? r1 : min(r1, mcnt - 1));
    const bf16* a_src0 = A + (size_t)arow0 * lda + kb + c8;
    const bf16* a_src1 = A + (size_t)arow1 * lda + kb + c8;
    const float* wbase = W + (size_t)n0 * ldw + kb;

    for (int k0 = 0; k0 < 512; k0 += 64) {
        bf16x8 a0 = *(const bf16x8*)(a_src0 + k0);
        bf16x8 a1 = *(const bf16x8*)(a_src1 + k0);
        *(bf16x8*)&As[r0][c8] = a0;
        *(bf16x8*)&As[r1][c8] = a1;
        #pragma unroll
        for (int s = 0; s < 2; ++s) {
            int r = r0 + s * 32;
            const float* pb = wbase + (size_t)r * ldw + k0 + c8;
            float4 b0 = *(const float4*)pb, b1 = *(const float4*)(pb + 4);
            bf16x8 bb = { (bf16)b0.x,(bf16)b0.y,(bf16)b0.z,(bf16)b0.w,
                          (bf16)b1.x,(bf16)b1.y,(bf16)b1.z,(bf16)b1.w };
            *(bf16x8*)&Bs[r][c8] = bb;
        }
        __syncthreads();
        #pragma unroll
        for (int ks = 0; ks < 2; ++ks) {
            bf16x8 fa0 = *(const bf16x8*)&As[wm * 32 + lr][ks * 32 + lk8];
            bf16x8 fa1 = *(const bf16x8*)&As[wm * 32 + 16 + lr][ks * 32 + lk8];
            bf16x8 fb0 = *(const bf16x8*)&Bs[wn * 32 + lr][ks * 32 + lk8];
            bf16x8 fb1 = *(const bf16x8*)&Bs[wn * 32 + 16 + lr][ks * 32 + lk8];
            acc[0][0] = MFMA(fa0, fb0, acc[0][0]);
            acc[0][1] = MFMA(fa0, fb1, acc[0][1]);
            acc[1][0] = MFMA(fa1, fb0, acc[1][0]);
            acc[1][1] = MFMA(fa1, fb1, acc[1][1]);
        }
        __syncthreads();
    }

    #pragma unroll
    for (int mi = 0; mi < 2; ++mi) {
        #pragma unroll
        for (int j = 0; j < 4; ++j) {
            int rl = wm * 32 + mi * 16 + (lane >> 4) * 4 + j;
            if (rl < mcnt) {
                if (sh) {
                    #pragma unroll
                    for (int ni = 0; ni < 2; ++ni)
                        atomicAdd(&out[(size_t)(m0 + rl) * H_DIM + n0 + wn * 32 + ni * 16 + lr],
                                  acc[mi][ni][j]);
                } else {
                    int t = row_token[m0 + rl];
                    float wt = row_w[m0 + rl];
                    #pragma unroll
                    for (int ni = 0; ni < 2; ++ni)
                        atomicAdd(&out[(size_t)t * H_DIM + n0 + wn * 32 + ni * 16 + lr],
                                  wt * acc[mi][ni][j]);
                }
            }
        }
    }
}

extern "C" void kernel_launch(void* const* d_in, const int* in_sizes, int n_in,
                              void* d_out, int out_size, void* d_ws, size_t ws_size,
                              hipStream_t stream)
{
    (void)in_sizes; (void)n_in; (void)out_size; (void)ws_size;
    const float* x    = (const float*)d_in[0];
    const float* gw   = (const float*)d_in[1];
    const float* bias = (const float*)d_in[2];
    const float* wgu  = (const float*)d_in[3];
    const float* wd   = (const float*)d_in[4];
    const float* sgu  = (const float*)d_in[5];
    const float* sd   = (const float*)d_in[6];
    float* out = (float*)d_out;

    char* ws = (char*)d_ws;
    int*   offs_g    = (int*)(ws);            // 17 ints
    int*   n_gu      = (int*)(ws + 128);
    int*   n_dn      = (int*)(ws + 132);
    int*   wl_gu     = (int*)(ws + 256);      // up to 640 ints
    int*   wl_dn     = (int*)(ws + 4096);     // up to 1280 ints
    int*   tok_e     = (int*)(ws + 16384);
    float* tok_w     = (float*)(ws + 24576);
    int*   row_token = (int*)(ws + 32768);
    float* row_w     = (float*)(ws + 40960);
    bf16*  xb        = (bf16*)(ws + 65536);
    bf16*  act       = (bf16*)(ws + 65536 + (1 << 21));
    bf16*  act2      = (bf16*)(ws + 65536 + (2 << 21));

    hipMemsetAsync(out, 0, (size_t)T_TOK * H_DIM * sizeof(float), stream);
    k_cast_router<<<T_TOK / 4, 256, 0, stream>>>(x, gw, bias, xb, tok_e, tok_w);
    k_build<<<1, 256, 0, stream>>>(tok_e, tok_w, offs_g, row_token, row_w,
                                   wl_gu, n_gu, wl_dn, n_dn);
    k_gu_all<<<GU_GRID, 256, 0, stream>>>(xb, wgu, sgu, act, act2,
                                          offs_g, row_token, wl_gu, n_gu);
    k_dn_all<<<DN_GRID, 256, 0, stream>>>(act, act2, wd, sd, out,
                                          offs_g, row_token, row_w, wl_dn, n_dn);
}